// Round 14
// baseline (303.388 us; speedup 1.0000x reference)
//
#include <hip/hip_runtime.h>

// Problem constants
#define BB 2
#define SS 2048
#define DD 1024
#define HH 16
#define HD 64
#define CS 512
#define NC 4
#define TD 3072            // 3*D
#define MM 4096            // B*S tokens

typedef __attribute__((ext_vector_type(8))) short short8;
typedef __attribute__((ext_vector_type(4))) float floatx4;
typedef __attribute__((ext_vector_type(2))) unsigned int uintx2;

__device__ __forceinline__ float bf2f(unsigned short h) {
  union { unsigned int u; float f; } v; v.u = ((unsigned int)h) << 16; return v.f;
}
__device__ __forceinline__ unsigned short f2bf(float f) {
  union { float f; unsigned int u; } v; v.f = f;
  unsigned int r = (v.u + 0x7fffu + ((v.u >> 16) & 1u)) >> 16;
  return (unsigned short)r;
}
__device__ __forceinline__ short8 ld8f(const float* p) {
  floatx4 f0 = *(const floatx4*)p;
  floatx4 f1 = *(const floatx4*)(p + 4);
  short8 o;
  o[0] = (short)f2bf(f0[0]); o[1] = (short)f2bf(f0[1]);
  o[2] = (short)f2bf(f0[2]); o[3] = (short)f2bf(f0[3]);
  o[4] = (short)f2bf(f1[0]); o[5] = (short)f2bf(f1[1]);
  o[6] = (short)f2bf(f1[2]); o[7] = (short)f2bf(f1[3]);
  return o;
}
// exact bf16 *= 0.125 (exponent shift; RNE of exact value)
__device__ __forceinline__ short8 scale8_eighth(short8 a) {
  short8 o;
#pragma unroll
  for (int j = 0; j < 8; ++j) o[j] = (short)f2bf(bf2f((unsigned short)a[j]) * 0.125f);
  return o;
}
__device__ __forceinline__ void async16(const void* g, void* l) {
  __builtin_amdgcn_global_load_lds((const __attribute__((address_space(1))) void*)g,
                                   (__attribute__((address_space(3))) void*)l, 16, 0, 0);
}

// ---------------------------------------------------------------------------
// Fused f32 -> bf16 convert for 4 segments (sizes in 2048-elem blocks)
// ---------------------------------------------------------------------------
__global__ __launch_bounds__(256) void cvt_all(
    const float* __restrict__ s0, unsigned short* __restrict__ d0, int n0,
    const float* __restrict__ s1, unsigned short* __restrict__ d1, int n1,
    const float* __restrict__ s2, unsigned short* __restrict__ d2, int n2,
    const float* __restrict__ s3, unsigned short* __restrict__ d3, int n3) {
  int bb = blockIdx.x;
  const float* s; unsigned short* d; int off;
  if (bb < n0) { s = s0; d = d0; off = bb; }
  else if (bb < n0 + n1) { s = s1; d = d1; off = bb - n0; }
  else if (bb < n0 + n1 + n2) { s = s2; d = d2; off = bb - n0 - n1; }
  else { s = s3; d = d3; off = bb - n0 - n1 - n2; }
  int i = (off * 256 + threadIdx.x) * 8;
  *(short8*)(d + i) = ld8f(s + i);
}

__global__ __launch_bounds__(256) void cvt_bf16(const float* __restrict__ in,
                                                unsigned short* __restrict__ out, int n) {
  int i = (blockIdx.x * 256 + threadIdx.x) * 8;
  if (i < n) *(short8*)(out + i) = ld8f(in + i);
}

// ---------------------------------------------------------------------------
// GEMM: C[M,N] = A[M,K] * W[N,K]^T + bias[N]. bf16 in (global_load_lds),
// C f32 or bf16. MT x 128 tile, 256 threads (2x2 waves).
// BK=64 — 32 MFMA per barrier-pair, XOR-swizzled LDS (R4 WIN).
// R10: XCD-aware chunked block swizzle (bijective; nwg%8==0) — kept.
// ---------------------------------------------------------------------------
template <int MT, int C_F32>
__global__ __launch_bounds__(256) void gemm_bt_bias(
    const unsigned short* __restrict__ A, const unsigned short* __restrict__ W,
    const float* __restrict__ bias, void* __restrict__ Cv, int M, int N, int K) {
  constexpr int AI = MT / 32;  // A-frags per wave
  __shared__ unsigned short sA[MT * 64];
  __shared__ unsigned short sB[128 * 64];
  const int tid = threadIdx.x;
  const int wid = tid >> 6, lane = tid & 63;
  const int quad = lane >> 4, l15 = lane & 15;
  const int wm = wid & 1, wn = wid >> 1;

  // XCD-aware remap: physical ids round-robin XCDs; give each XCD a
  // contiguous chunk of logical tile ids. Bijective (nwg % 8 == 0).
  const int nwg = gridDim.x * gridDim.y;
  int bid = blockIdx.y * gridDim.x + blockIdx.x;
  bid = (bid & 7) * (nwg >> 3) + (bid >> 3);
  const int bm = bid / gridDim.x, bn = bid % gridDim.x;

  floatx4 acc[AI][4];
#pragma unroll
  for (int i = 0; i < AI; ++i)
#pragma unroll
    for (int j = 0; j < 4; ++j) acc[i][j] = (floatx4){0.f, 0.f, 0.f, 0.f};

  const int rb = tid >> 3;                        // 0..31
  const int colsw = ((tid & 7) ^ (rb & 7)) << 3;  // pre-swizzled k-offset
  const unsigned short* gA = A + (size_t)(bm * MT + rb) * K + colsw;
  const unsigned short* gW = W + (size_t)(bn * 128 + rb) * K + colsw;
  unsigned short* lA = sA + wid * 512;  // wave-uniform base; HW appends lane*16B
  unsigned short* lB = sB + wid * 512;

  for (int k0 = 0; k0 < K; k0 += 64) {
#pragma unroll
    for (int i = 0; i < MT / 32; ++i)
      async16(gA + (size_t)(i * 32) * K + k0, lA + i * 2048);
#pragma unroll
    for (int i = 0; i < 4; ++i)
      async16(gW + (size_t)(i * 32) * K + k0, lB + i * 2048);
    __syncthreads();

#pragma unroll
    for (int kk = 0; kk < 2; ++kk) {
      short8 af[AI], bfr[4];
#pragma unroll
      for (int i = 0; i < AI; ++i) {
        int row = wm * (MT / 2) + i * 16 + l15;
        af[i] = *(const short8*)(sA + row * 64 + ((((kk << 2) | quad) ^ (row & 7)) << 3));
      }
#pragma unroll
      for (int j = 0; j < 4; ++j) {
        int row = wn * 64 + j * 16 + l15;
        bfr[j] = *(const short8*)(sB + row * 64 + ((((kk << 2) | quad) ^ (row & 7)) << 3));
      }
#pragma unroll
      for (int i = 0; i < AI; ++i)
#pragma unroll
        for (int j = 0; j < 4; ++j)
          acc[i][j] = __builtin_amdgcn_mfma_f32_16x16x32_bf16(af[i], bfr[j], acc[i][j], 0, 0, 0);
    }
    __syncthreads();
  }

  // Epilogue. C/D layout: col = lane&15, row = quad*4 + reg.
#pragma unroll
  for (int j = 0; j < 4; ++j) {
    int n = bn * 128 + wn * 64 + j * 16 + l15;
    float bv = bias[n];
#pragma unroll
    for (int i = 0; i < AI; ++i) {
      int mrow = bm * MT + wm * (MT / 2) + i * 16 + quad * 4;
#pragma unroll
      for (int rr = 0; rr < 4; ++rr) {
        float v = acc[i][j][rr] + bv;
        if (C_F32) ((float*)Cv)[(size_t)(mrow + rr) * N + n] = v;
        else ((unsigned short*)Cv)[(size_t)(mrow + rr) * N + n] = f2bf(v);
      }
    }
  }
}

// ---------------------------------------------------------------------------
// Local attention: seq len nc=4 across chunks, one wave per (b,c,h).
// ---------------------------------------------------------------------------
__global__ __launch_bounds__(256) void attn_local(const unsigned short* __restrict__ QKV,
                                                  unsigned short* __restrict__ O) {
  const int tid = threadIdx.x;
  const int wid = tid >> 6, lane = tid & 63;
  const int idx = blockIdx.x * 4 + wid;  // (b*512 + c)*16 + h
  const int h = idx & 15, c = (idx >> 4) & 511, b = idx >> 13;

  float q[NC], k[NC], v[NC];
#pragma unroll
  for (int n = 0; n < NC; ++n) {
    size_t base = (size_t)(b * SS + n * CS + c) * TD + h * HD + lane;
    q[n] = bf2f(QKV[base]);
    k[n] = bf2f(QKV[base + DD]);
    v[n] = bf2f(QKV[base + 2 * DD]);
  }
  float s[NC][NC];
#pragma unroll
  for (int m = 0; m < NC; ++m)
#pragma unroll
    for (int n = 0; n < NC; ++n) {
      float p = q[m] * k[n];
#pragma unroll
      for (int off = 32; off >= 1; off >>= 1) p += __shfl_xor(p, off);
      s[m][n] = p * 0.125f;
    }
#pragma unroll
  for (int m = 0; m < NC; ++m) {
    float mx = fmaxf(fmaxf(s[m][0], s[m][1]), fmaxf(s[m][2], s[m][3]));
    float e[NC], sum = 0.f;
#pragma unroll
    for (int n = 0; n < NC; ++n) { e[n] = __expf(s[m][n] - mx); sum += e[n]; }
    float o = (e[0] * v[0] + e[1] * v[1] + e[2] * v[2] + e[3] * v[3]) / sum;
    O[(size_t)(m * (BB * CS) + b * CS + c) * DD + h * HD + lane] = f2bf(o);
  }
}

// ---------------------------------------------------------------------------
// V pre-transpose: QKV2 V-columns -> VT[b][h][dim(64)][token(2048)].
// ---------------------------------------------------------------------------
__global__ __launch_bounds__(256) void transpose_v(const unsigned short* __restrict__ QKV,
                                                   unsigned short* __restrict__ VT) {
  __shared__ unsigned short sT[64 * 64];
  const int tid = threadIdx.x;
  const int bh = blockIdx.x, b = bh >> 4, h = bh & 15;
  const int s0 = blockIdx.y * 64;
#pragma unroll
  for (int it = 0; it < 2; ++it) {
    int C = it * 256 + tid;
    int t = C >> 3, dc = C & 7;
    short8 v = *(const short8*)(QKV + (size_t)(b * SS + s0 + t) * TD + 2 * DD + h * HD + dc * 8);
    *(short8*)(sT + t * 64 + ((dc ^ (t & 7)) << 3)) = v;
  }
  __syncthreads();
#pragma unroll
  for (int it = 0; it < 2; ++it) {
    int C = it * 256 + tid;
    int d = C >> 3, tc = C & 7;
    short8 o;
#pragma unroll
    for (int j = 0; j < 8; ++j) {
      int t = tc * 8 + j;
      o[j] = (short)sT[t * 64 + (((d >> 3) ^ (t & 7)) << 3) + (d & 7)];
    }
    *(short8*)(VT + ((size_t)(bh * 64 + d)) * SS + s0 + tc * 8) = o;
  }
}

// ---------------------------------------------------------------------------
// Global attention — FINAL (best-known: 55.3us, total 298.0us).
// R7 structure + T5 setprio (R13 A/B: consistent small win).
//  - Swapped QK^T (mfma(K,Q)); lane holds P for q-row l15 -> P in registers,
//    packed into PV A-frags with key-slot permutation pi; V B-frag reads the
//    same pi via 2x ds_read_b64 (2-way conflict: absorbed, R8 A/B-proven).
//  - K,V staged via global_load_lds, single-buffered, inverse-swizzled src.
//  - LDS 33.3KB, 4 blocks/CU via __launch_bounds__(256,4); VGPR 64.
//  [Session ledger: R1/R9 spill => never cap <128 VGPR, watch WRITE_SIZE;
//   R2/R3 pinned schedules regress; R5 2/CU regresses; R8 V-conflict fix
//   time-neutral (absorbed); R11 direct-global V regresses 2.5x (8B/lane at
//   4KB lane stride = 64 lines/instr; LDS-bypass needs coalesced pattern);
//   R4 BK=64 GEMM WIN; R7 reg-P WIN -30us; R10 XCD swizzle ~+1; R13 setprio
//   small win. Dead by arithmetic: 5th block/CU (grid=4x256 exactly),
//   256^2 8-phase (192 blocks < 256 CU), stream overlap (in-place buffers).]
// ---------------------------------------------------------------------------
__global__ __launch_bounds__(256, 4) void attn_global(
    const unsigned short* __restrict__ Q, const unsigned short* __restrict__ Kp,
    const unsigned short* __restrict__ VT, unsigned short* __restrict__ O) {
  __shared__ unsigned short sK[2][64 * 64];   // [khalf][key][dimchunk ^ (key&7)]
  __shared__ unsigned short sVT[2][64 * 64];  // [khalf][dim][keychunk ^ (dim&7)]
  __shared__ float lsb[2][64];                // [khalf][qhalf*32+g*16+row]
  const int tid = threadIdx.x;
  const int wid = tid >> 6, lane = tid & 63;
  const int quad = lane >> 4, l15 = lane & 15;
  const int qhalf = wid & 1, khalf = wid >> 1;
  const int bh = blockIdx.x;
  const int b = bh >> 4, h = bh & 15;
  const int q0 = blockIdx.y * 64 + qhalf * 32;

  // Q B-frags, pre-scaled by 1/8 (exact)
  short8 qf[2][2];
#pragma unroll
  for (int g = 0; g < 2; ++g) {
    const unsigned short* qr = Q + (size_t)(b * SS + q0 + g * 16 + l15) * TD + h * HD + quad * 8;
    qf[g][0] = scale8_eighth(*(const short8*)qr);
    qf[g][1] = scale8_eighth(*(const short8*)(qr + 32));
  }

  float lsum[2] = {0.f, 0.f};
  floatx4 oacc[2][4];
#pragma unroll
  for (int g = 0; g < 2; ++g)
#pragma unroll
    for (int s = 0; s < 4; ++s) oacc[g][s] = (floatx4){0.f, 0.f, 0.f, 0.f};

  const unsigned short* myK = &sK[khalf][0];
  const unsigned short* myV = &sVT[khalf][0];
  const unsigned short* vbase = VT + (size_t)(bh * 64) * SS;

  // Staging: linear LDS dest (global_load_lds) + inverse-swizzled source.
  unsigned int koff[2], voff[2];  // per-thread source offsets (shorts)
#pragma unroll
  for (int it = 0; it < 2; ++it) {
    const int P = it * 256 + tid;
    const int row = P >> 3, s = P & 7;
    koff[it] = (unsigned int)((b * SS + row) * TD + h * HD + ((s ^ (row & 7)) << 3));
    voff[it] = (unsigned int)(row * SS + ((s ^ (row & 7)) << 3));
  }

  for (int t = 0; t < 16; ++t) {
    // stage both khalf K and V tiles via global_load_lds (barrier drains)
#pragma unroll
    for (int kh = 0; kh < 2; ++kh) {
      const int kbase = (kh * 16 + t) * 64;  // token offset of this tile
#pragma unroll
      for (int it = 0; it < 2; ++it) {
        async16(Kp + (size_t)kbase * TD + koff[it], (unsigned short*)&sK[kh][0] + it * 2048 + wid * 512);
        async16(vbase + kbase + voff[it], (unsigned short*)&sVT[kh][0] + it * 2048 + wid * 512);
      }
    }
    __syncthreads();

    // S^T = K (Q/8)^T : C rows = keys (quad*4+rr), cols = q-row (l15)
    floatx4 sacc[2][4];
    __builtin_amdgcn_s_setprio(1);
#pragma unroll
    for (int sub = 0; sub < 4; ++sub) {
      int key = sub * 16 + l15;
      int c0 = (quad ^ (key & 7)) << 3;
      short8 kf0 = *(const short8*)(myK + key * 64 + c0);
      short8 kf1 = *(const short8*)(myK + key * 64 + (c0 ^ 32));
#pragma unroll
      for (int g = 0; g < 2; ++g) {
        floatx4 z = (floatx4){0.f, 0.f, 0.f, 0.f};
        z = __builtin_amdgcn_mfma_f32_16x16x32_bf16(kf0, qf[g][0], z, 0, 0, 0);
        z = __builtin_amdgcn_mfma_f32_16x16x32_bf16(kf1, qf[g][1], z, 0, 0, 0);
        sacc[g][sub] = z;
      }
    }
    __builtin_amdgcn_s_setprio(0);

    // exp + truncate to bf16, packed straight into PV A-frags (no LDS).
    // pf[g][c] slot j: j<4 -> key 32c+quad*4+j ; j>=4 -> key 32c+16+quad*4+j-4.
    short8 pf[2][2];
#pragma unroll
    for (int g = 0; g < 2; ++g)
#pragma unroll
      for (int c = 0; c < 2; ++c) {
        unsigned int w[4];
#pragma unroll
        for (int hs = 0; hs < 2; ++hs) {
          const floatx4 z = sacc[g][2 * c + hs];
          unsigned int u0 = __float_as_uint(__expf(z[0]));
          unsigned int u1 = __float_as_uint(__expf(z[1]));
          unsigned int u2 = __float_as_uint(__expf(z[2]));
          unsigned int u3 = __float_as_uint(__expf(z[3]));
          lsum[g] += __uint_as_float(u0 & 0xffff0000u);
          lsum[g] += __uint_as_float(u1 & 0xffff0000u);
          lsum[g] += __uint_as_float(u2 & 0xffff0000u);
          lsum[g] += __uint_as_float(u3 & 0xffff0000u);
          w[hs * 2 + 0] = (u0 >> 16) | (u1 & 0xffff0000u);
          w[hs * 2 + 1] = (u2 >> 16) | (u3 & 0xffff0000u);
        }
        union { unsigned int u[4]; short8 s; } pk;
        pk.u[0] = w[0]; pk.u[1] = w[1]; pk.u[2] = w[2]; pk.u[3] = w[3];
        pf[g][c] = pk.s;
      }

    // O += P * V. B-frag matches the pack permutation: two b64 reads per (sub,c).
    __builtin_amdgcn_s_setprio(1);
#pragma unroll
    for (int sub = 0; sub < 4; ++sub) {
      const int n = sub * 16 + l15;
      const int nsw = n & 7;
      const int inner = (quad & 1) * 4;  // shorts
      short8 vb[2];
#pragma unroll
      for (int c = 0; c < 2; ++c) {
        const int c8a = (((c << 2) | (quad >> 1)) ^ nsw);
        const int c8b = (((c << 2) | 2 | (quad >> 1)) ^ nsw);
        uintx2 a = *(const uintx2*)(myV + n * 64 + c8a * 8 + inner);
        uintx2 d = *(const uintx2*)(myV + n * 64 + c8b * 8 + inner);
        union { unsigned int u[4]; short8 s; } vk;
        vk.u[0] = a[0]; vk.u[1] = a[1]; vk.u[2] = d[0]; vk.u[3] = d[1];
        vb[c] = vk.s;
      }
#pragma unroll
      for (int g = 0; g < 2; ++g) {
        oacc[g][sub] = __builtin_amdgcn_mfma_f32_16x16x32_bf16(pf[g][0], vb[0], oacc[g][sub], 0, 0, 0);
        oacc[g][sub] = __builtin_amdgcn_mfma_f32_16x16x32_bf16(pf[g][1], vb[1], oacc[g][sub], 0, 0, 0);
      }
    }
    __builtin_amdgcn_s_setprio(0);
    __syncthreads();  // all reads done; next iter restages
  }

  // lsum: reduce across quads -> full khalf row-sum, replicated.
  float lh[2];
#pragma unroll
  for (int g = 0; g < 2; ++g) {
    float s = lsum[g];
    s += __shfl_xor(s, 16);
    s += __shfl_xor(s, 32);
    lh[g] = s;
  }
  if (lane < 16) {
#pragma unroll
    for (int g = 0; g < 2; ++g) lsb[khalf][qhalf * 32 + g * 16 + l15] = lh[g];
  }

  // cross-khalf merge; sK (dead) reused as the f32 O-partial buffer.
  float* obuf = (float*)&sK[0][0];
  if (khalf == 1) {
    float* my = obuf + qhalf * 2048;
#pragma unroll
    for (int g = 0; g < 2; ++g)
#pragma unroll
      for (int sub = 0; sub < 4; ++sub)
#pragma unroll
        for (int rr = 0; rr < 4; ++rr)
          my[(g * 16 + quad * 4 + rr) * 64 + sub * 16 + l15] = oacc[g][sub][rr];
  }
  __syncthreads();
  if (khalf == 0) {
    float* my = obuf + qhalf * 2048;
#pragma unroll
    for (int g = 0; g < 2; ++g) {
      float inv[4];
#pragma unroll
      for (int rr = 0; rr < 4; ++rr) {
        int idx = qhalf * 32 + g * 16 + quad * 4 + rr;
        inv[rr] = 1.f / (lsb[0][idx] + lsb[1][idx]);
      }
#pragma unroll
      for (int sub = 0; sub < 4; ++sub)
#pragma unroll
        for (int rr = 0; rr < 4; ++rr) {
          float v = oacc[g][sub][rr] + my[(g * 16 + quad * 4 + rr) * 64 + sub * 16 + l15];
          int row = b * SS + q0 + g * 16 + quad * 4 + rr;
          O[(size_t)row * DD + h * HD + sub * 16 + l15] = f2bf(v * inv[rr]);
        }
    }
  }
}

// ---------------------------------------------------------------------------
// Memory plan (unchanged from R4).
// ---------------------------------------------------------------------------
extern "C" void kernel_launch(void* const* d_in, const int* in_sizes, int n_in,
                              void* d_out, int out_size, void* d_ws, size_t ws_size,
                              hipStream_t stream) {
  const float* x       = (const float*)d_in[0];
  const float* w_in_l  = (const float*)d_in[1];
  const float* b_in_l  = (const float*)d_in[2];
  const float* w_out_l = (const float*)d_in[3];
  const float* b_out_l = (const float*)d_in[4];
  const float* w_in_g  = (const float*)d_in[5];
  const float* b_in_g  = (const float*)d_in[6];
  const float* w_out_g = (const float*)d_in[7];
  const float* b_out_g = (const float*)d_in[8];

  unsigned short* wsA = (unsigned short*)d_ws;            // 12M shorts
  unsigned short* wsB = wsA + (size_t)MM * TD;            // 4M shorts
  unsigned short* dob = (unsigned short*)d_out;           // 8M shorts
  unsigned short* wbf_out_l = dob;                        // 1M sh
  unsigned short* wbf_in_g  = dob + (size_t)DD * DD;      // 3M sh
  unsigned short* wbf_in_l  = dob + 4 * (size_t)DD * DD;  // 3M sh
  unsigned short* o1        = dob + 4 * (size_t)DD * DD;  // 4M sh (after g1)
  unsigned short* vtbuf     = dob;                        // 4M sh (after g4)

  dim3 blk(256);
  // fused weight/x converts: 512 + 1536 + 1536 + 2048 = 5632 blocks
  cvt_all<<<dim3(5632), blk, 0, stream>>>(w_out_l, wbf_out_l, 512,
                                          w_in_g, wbf_in_g, 1536,
                                          w_in_l, wbf_in_l, 1536,
                                          x, wsB, 2048);

  // 1) QKV1 = x @ w_in_l^T + b_in_l  (768 blocks, XCD-swizzled)
  gemm_bt_bias<128, 0><<<dim3(TD / 128, MM / 128), blk, 0, stream>>>(wsB, wbf_in_l, b_in_l, wsA, MM, TD, DD);
  // 2) local attention (rows pre-permuted for the reshape trick)
  attn_local<<<dim3(BB * CS * HH / 4), blk, 0, stream>>>(wsA, o1);
  // 3) loc2 = O1 @ w_out_l^T + b_out_l  (MT=64, 512 blocks, XCD-swizzled)
  gemm_bt_bias<64, 0><<<dim3(DD / 128, MM / 64), blk, 0, stream>>>(o1, wbf_out_l, b_out_l, wsB, MM, DD, DD);
  // 4) QKV2 = loc2 @ w_in_g^T + b_in_g  (768 blocks, XCD-swizzled)
  gemm_bt_bias<128, 0><<<dim3(TD / 128, MM / 128), blk, 0, stream>>>(wsB, wbf_in_g, b_in_g, wsA, MM, TD, DD);
  // 5a) V pre-transpose
  transpose_v<<<dim3(BB * HH, SS / 64), blk, 0, stream>>>(wsA, vtbuf);
  // 5b) global attention (final: reg-P, DMA staging, 4 blocks/CU, setprio)
  attn_global<<<dim3(BB * HH, SS / 64), blk, 0, stream>>>(wsA, wsA + DD, vtbuf, wsB);
  // 5c) convert w_out_g into dead QKV2 space
  cvt_bf16<<<dim3(DD * DD / 2048), blk, 0, stream>>>(w_out_g, wsA, DD * DD);
  // 6) out = O2 @ w_out_g^T + b_out_g  (f32 out, MT=64, XCD-swizzled)
  gemm_bt_bias<64, 1><<<dim3(DD / 128, MM / 64), blk, 0, stream>>>(wsB, wsA, b_out_g, d_out, MM, DD, DD);
}

// Round 15
// 296.807 us; speedup vs baseline: 1.0222x; 1.0222x over previous
//
#include <hip/hip_runtime.h>

// Problem constants
#define BB 2
#define SS 2048
#define DD 1024
#define HH 16
#define HD 64
#define CS 512
#define NC 4
#define TD 3072            // 3*D
#define MM 4096            // B*S tokens

typedef __attribute__((ext_vector_type(8))) short short8;
typedef __attribute__((ext_vector_type(4))) float floatx4;
typedef __attribute__((ext_vector_type(2))) unsigned int uintx2;

__device__ __forceinline__ float bf2f(unsigned short h) {
  union { unsigned int u; float f; } v; v.u = ((unsigned int)h) << 16; return v.f;
}
__device__ __forceinline__ unsigned short f2bf(float f) {
  union { float f; unsigned int u; } v; v.f = f;
  unsigned int r = (v.u + 0x7fffu + ((v.u >> 16) & 1u)) >> 16;
  return (unsigned short)r;
}
__device__ __forceinline__ short8 ld8f(const float* p) {
  floatx4 f0 = *(const floatx4*)p;
  floatx4 f1 = *(const floatx4*)(p + 4);
  short8 o;
  o[0] = (short)f2bf(f0[0]); o[1] = (short)f2bf(f0[1]);
  o[2] = (short)f2bf(f0[2]); o[3] = (short)f2bf(f0[3]);
  o[4] = (short)f2bf(f1[0]); o[5] = (short)f2bf(f1[1]);
  o[6] = (short)f2bf(f1[2]); o[7] = (short)f2bf(f1[3]);
  return o;
}
// exact bf16 *= 0.125 (exponent shift; RNE of exact value)
__device__ __forceinline__ short8 scale8_eighth(short8 a) {
  short8 o;
#pragma unroll
  for (int j = 0; j < 8; ++j) o[j] = (short)f2bf(bf2f((unsigned short)a[j]) * 0.125f);
  return o;
}
__device__ __forceinline__ void async16(const void* g, void* l) {
  __builtin_amdgcn_global_load_lds((const __attribute__((address_space(1))) void*)g,
                                   (__attribute__((address_space(3))) void*)l, 16, 0, 0);
}

// ---------------------------------------------------------------------------
// Fused f32 -> bf16 convert for 4 segments (sizes in 2048-elem blocks)
// ---------------------------------------------------------------------------
__global__ __launch_bounds__(256) void cvt_all(
    const float* __restrict__ s0, unsigned short* __restrict__ d0, int n0,
    const float* __restrict__ s1, unsigned short* __restrict__ d1, int n1,
    const float* __restrict__ s2, unsigned short* __restrict__ d2, int n2,
    const float* __restrict__ s3, unsigned short* __restrict__ d3, int n3) {
  int bb = blockIdx.x;
  const float* s; unsigned short* d; int off;
  if (bb < n0) { s = s0; d = d0; off = bb; }
  else if (bb < n0 + n1) { s = s1; d = d1; off = bb - n0; }
  else if (bb < n0 + n1 + n2) { s = s2; d = d2; off = bb - n0 - n1; }
  else { s = s3; d = d3; off = bb - n0 - n1 - n2; }
  int i = (off * 256 + threadIdx.x) * 8;
  *(short8*)(d + i) = ld8f(s + i);
}

__global__ __launch_bounds__(256) void cvt_bf16(const float* __restrict__ in,
                                                unsigned short* __restrict__ out, int n) {
  int i = (blockIdx.x * 256 + threadIdx.x) * 8;
  if (i < n) *(short8*)(out + i) = ld8f(in + i);
}

// ---------------------------------------------------------------------------
// GEMM: C[M,N] = A[M,K] * W[N,K]^T + bias[N]. bf16 in (global_load_lds),
// C f32 or bf16. MT x 128 tile, 256 threads (2x2 waves).
// BK=64 — 32 MFMA per barrier-pair, XOR-swizzled LDS (R4 WIN).
// R10: XCD-aware chunked block swizzle (bijective; nwg%8==0) — kept.
// ---------------------------------------------------------------------------
template <int MT, int C_F32>
__global__ __launch_bounds__(256) void gemm_bt_bias(
    const unsigned short* __restrict__ A, const unsigned short* __restrict__ W,
    const float* __restrict__ bias, void* __restrict__ Cv, int M, int N, int K) {
  constexpr int AI = MT / 32;  // A-frags per wave
  __shared__ unsigned short sA[MT * 64];
  __shared__ unsigned short sB[128 * 64];
  const int tid = threadIdx.x;
  const int wid = tid >> 6, lane = tid & 63;
  const int quad = lane >> 4, l15 = lane & 15;
  const int wm = wid & 1, wn = wid >> 1;

  // XCD-aware remap: physical ids round-robin XCDs; give each XCD a
  // contiguous chunk of logical tile ids. Bijective (nwg % 8 == 0).
  const int nwg = gridDim.x * gridDim.y;
  int bid = blockIdx.y * gridDim.x + blockIdx.x;
  bid = (bid & 7) * (nwg >> 3) + (bid >> 3);
  const int bm = bid / gridDim.x, bn = bid % gridDim.x;

  floatx4 acc[AI][4];
#pragma unroll
  for (int i = 0; i < AI; ++i)
#pragma unroll
    for (int j = 0; j < 4; ++j) acc[i][j] = (floatx4){0.f, 0.f, 0.f, 0.f};

  const int rb = tid >> 3;                        // 0..31
  const int colsw = ((tid & 7) ^ (rb & 7)) << 3;  // pre-swizzled k-offset
  const unsigned short* gA = A + (size_t)(bm * MT + rb) * K + colsw;
  const unsigned short* gW = W + (size_t)(bn * 128 + rb) * K + colsw;
  unsigned short* lA = sA + wid * 512;  // wave-uniform base; HW appends lane*16B
  unsigned short* lB = sB + wid * 512;

  for (int k0 = 0; k0 < K; k0 += 64) {
#pragma unroll
    for (int i = 0; i < MT / 32; ++i)
      async16(gA + (size_t)(i * 32) * K + k0, lA + i * 2048);
#pragma unroll
    for (int i = 0; i < 4; ++i)
      async16(gW + (size_t)(i * 32) * K + k0, lB + i * 2048);
    __syncthreads();

#pragma unroll
    for (int kk = 0; kk < 2; ++kk) {
      short8 af[AI], bfr[4];
#pragma unroll
      for (int i = 0; i < AI; ++i) {
        int row = wm * (MT / 2) + i * 16 + l15;
        af[i] = *(const short8*)(sA + row * 64 + ((((kk << 2) | quad) ^ (row & 7)) << 3));
      }
#pragma unroll
      for (int j = 0; j < 4; ++j) {
        int row = wn * 64 + j * 16 + l15;
        bfr[j] = *(const short8*)(sB + row * 64 + ((((kk << 2) | quad) ^ (row & 7)) << 3));
      }
#pragma unroll
      for (int i = 0; i < AI; ++i)
#pragma unroll
        for (int j = 0; j < 4; ++j)
          acc[i][j] = __builtin_amdgcn_mfma_f32_16x16x32_bf16(af[i], bfr[j], acc[i][j], 0, 0, 0);
    }
    __syncthreads();
  }

  // Epilogue. C/D layout: col = lane&15, row = quad*4 + reg.
#pragma unroll
  for (int j = 0; j < 4; ++j) {
    int n = bn * 128 + wn * 64 + j * 16 + l15;
    float bv = bias[n];
#pragma unroll
    for (int i = 0; i < AI; ++i) {
      int mrow = bm * MT + wm * (MT / 2) + i * 16 + quad * 4;
#pragma unroll
      for (int rr = 0; rr < 4; ++rr) {
        float v = acc[i][j][rr] + bv;
        if (C_F32) ((float*)Cv)[(size_t)(mrow + rr) * N + n] = v;
        else ((unsigned short*)Cv)[(size_t)(mrow + rr) * N + n] = f2bf(v);
      }
    }
  }
}

// ---------------------------------------------------------------------------
// Local attention: seq len nc=4 across chunks, one wave per (b,c,h).
// ---------------------------------------------------------------------------
__global__ __launch_bounds__(256) void attn_local(const unsigned short* __restrict__ QKV,
                                                  unsigned short* __restrict__ O) {
  const int tid = threadIdx.x;
  const int wid = tid >> 6, lane = tid & 63;
  const int idx = blockIdx.x * 4 + wid;  // (b*512 + c)*16 + h
  const int h = idx & 15, c = (idx >> 4) & 511, b = idx >> 13;

  float q[NC], k[NC], v[NC];
#pragma unroll
  for (int n = 0; n < NC; ++n) {
    size_t base = (size_t)(b * SS + n * CS + c) * TD + h * HD + lane;
    q[n] = bf2f(QKV[base]);
    k[n] = bf2f(QKV[base + DD]);
    v[n] = bf2f(QKV[base + 2 * DD]);
  }
  float s[NC][NC];
#pragma unroll
  for (int m = 0; m < NC; ++m)
#pragma unroll
    for (int n = 0; n < NC; ++n) {
      float p = q[m] * k[n];
#pragma unroll
      for (int off = 32; off >= 1; off >>= 1) p += __shfl_xor(p, off);
      s[m][n] = p * 0.125f;
    }
#pragma unroll
  for (int m = 0; m < NC; ++m) {
    float mx = fmaxf(fmaxf(s[m][0], s[m][1]), fmaxf(s[m][2], s[m][3]));
    float e[NC], sum = 0.f;
#pragma unroll
    for (int n = 0; n < NC; ++n) { e[n] = __expf(s[m][n] - mx); sum += e[n]; }
    float o = (e[0] * v[0] + e[1] * v[1] + e[2] * v[2] + e[3] * v[3]) / sum;
    O[(size_t)(m * (BB * CS) + b * CS + c) * DD + h * HD + lane] = f2bf(o);
  }
}

// ---------------------------------------------------------------------------
// V pre-transpose: QKV2 V-columns -> VT[b][h][dim(64)][token(2048)].
// ---------------------------------------------------------------------------
__global__ __launch_bounds__(256) void transpose_v(const unsigned short* __restrict__ QKV,
                                                   unsigned short* __restrict__ VT) {
  __shared__ unsigned short sT[64 * 64];
  const int tid = threadIdx.x;
  const int bh = blockIdx.x, b = bh >> 4, h = bh & 15;
  const int s0 = blockIdx.y * 64;
#pragma unroll
  for (int it = 0; it < 2; ++it) {
    int C = it * 256 + tid;
    int t = C >> 3, dc = C & 7;
    short8 v = *(const short8*)(QKV + (size_t)(b * SS + s0 + t) * TD + 2 * DD + h * HD + dc * 8);
    *(short8*)(sT + t * 64 + ((dc ^ (t & 7)) << 3)) = v;
  }
  __syncthreads();
#pragma unroll
  for (int it = 0; it < 2; ++it) {
    int C = it * 256 + tid;
    int d = C >> 3, tc = C & 7;
    short8 o;
#pragma unroll
    for (int j = 0; j < 8; ++j) {
      int t = tc * 8 + j;
      o[j] = (short)sT[t * 64 + (((d >> 3) ^ (t & 7)) << 3) + (d & 7)];
    }
    *(short8*)(VT + ((size_t)(bh * 64 + d)) * SS + s0 + tc * 8) = o;
  }
}

// ---------------------------------------------------------------------------
// Global attention — FINAL (session best: total 298.0us, attn 55.3-56.8us).
// R7 structure + T5 setprio (neutral-to-slightly-positive; kept, 4 instrs).
//  - Swapped QK^T (mfma(K,Q)); lane holds P for q-row l15 -> P in registers,
//    packed into PV A-frags with key-slot permutation pi; V B-frag reads the
//    same pi via 2x ds_read_b64 (2-way conflict: absorbed, R8 A/B-proven).
//  - K,V staged via global_load_lds, single-buffered, inverse-swizzled src.
//  - LDS 33.3KB, 4 blocks/CU via __launch_bounds__(256,4); VGPR 64.
//  [Session ledger: R1/R9 spill => never cap <128 VGPR, watch WRITE_SIZE;
//   R2/R3 pinned schedules regress; R5 2/CU regresses; R8 V-conflict fix
//   time-neutral (absorbed); R11 direct-global V regresses 2.5x (8B/lane at
//   4KB lane stride = 64 lines/instr; LDS-bypass needs coalesced pattern);
//   R4 BK=64 GEMM WIN; R7 reg-P WIN -30us; R10 XCD swizzle ~+1; noise band
//   +-3us (identical-source pairs R10/R12, R13/R14). Dead by arithmetic:
//   5th block/CU (grid=4x256 exactly), 256^2 8-phase (192 blocks < 256 CU),
//   stream overlap (in-place buffers).]
// ---------------------------------------------------------------------------
__global__ __launch_bounds__(256, 4) void attn_global(
    const unsigned short* __restrict__ Q, const unsigned short* __restrict__ Kp,
    const unsigned short* __restrict__ VT, unsigned short* __restrict__ O) {
  __shared__ unsigned short sK[2][64 * 64];   // [khalf][key][dimchunk ^ (key&7)]
  __shared__ unsigned short sVT[2][64 * 64];  // [khalf][dim][keychunk ^ (dim&7)]
  __shared__ float lsb[2][64];                // [khalf][qhalf*32+g*16+row]
  const int tid = threadIdx.x;
  const int wid = tid >> 6, lane = tid & 63;
  const int quad = lane >> 4, l15 = lane & 15;
  const int qhalf = wid & 1, khalf = wid >> 1;
  const int bh = blockIdx.x;
  const int b = bh >> 4, h = bh & 15;
  const int q0 = blockIdx.y * 64 + qhalf * 32;

  // Q B-frags, pre-scaled by 1/8 (exact)
  short8 qf[2][2];
#pragma unroll
  for (int g = 0; g < 2; ++g) {
    const unsigned short* qr = Q + (size_t)(b * SS + q0 + g * 16 + l15) * TD + h * HD + quad * 8;
    qf[g][0] = scale8_eighth(*(const short8*)qr);
    qf[g][1] = scale8_eighth(*(const short8*)(qr + 32));
  }

  float lsum[2] = {0.f, 0.f};
  floatx4 oacc[2][4];
#pragma unroll
  for (int g = 0; g < 2; ++g)
#pragma unroll
    for (int s = 0; s < 4; ++s) oacc[g][s] = (floatx4){0.f, 0.f, 0.f, 0.f};

  const unsigned short* myK = &sK[khalf][0];
  const unsigned short* myV = &sVT[khalf][0];
  const unsigned short* vbase = VT + (size_t)(bh * 64) * SS;

  // Staging: linear LDS dest (global_load_lds) + inverse-swizzled source.
  unsigned int koff[2], voff[2];  // per-thread source offsets (shorts)
#pragma unroll
  for (int it = 0; it < 2; ++it) {
    const int P = it * 256 + tid;
    const int row = P >> 3, s = P & 7;
    koff[it] = (unsigned int)((b * SS + row) * TD + h * HD + ((s ^ (row & 7)) << 3));
    voff[it] = (unsigned int)(row * SS + ((s ^ (row & 7)) << 3));
  }

  for (int t = 0; t < 16; ++t) {
    // stage both khalf K and V tiles via global_load_lds (barrier drains)
#pragma unroll
    for (int kh = 0; kh < 2; ++kh) {
      const int kbase = (kh * 16 + t) * 64;  // token offset of this tile
#pragma unroll
      for (int it = 0; it < 2; ++it) {
        async16(Kp + (size_t)kbase * TD + koff[it], (unsigned short*)&sK[kh][0] + it * 2048 + wid * 512);
        async16(vbase + kbase + voff[it], (unsigned short*)&sVT[kh][0] + it * 2048 + wid * 512);
      }
    }
    __syncthreads();

    // S^T = K (Q/8)^T : C rows = keys (quad*4+rr), cols = q-row (l15)
    floatx4 sacc[2][4];
    __builtin_amdgcn_s_setprio(1);
#pragma unroll
    for (int sub = 0; sub < 4; ++sub) {
      int key = sub * 16 + l15;
      int c0 = (quad ^ (key & 7)) << 3;
      short8 kf0 = *(const short8*)(myK + key * 64 + c0);
      short8 kf1 = *(const short8*)(myK + key * 64 + (c0 ^ 32));
#pragma unroll
      for (int g = 0; g < 2; ++g) {
        floatx4 z = (floatx4){0.f, 0.f, 0.f, 0.f};
        z = __builtin_amdgcn_mfma_f32_16x16x32_bf16(kf0, qf[g][0], z, 0, 0, 0);
        z = __builtin_amdgcn_mfma_f32_16x16x32_bf16(kf1, qf[g][1], z, 0, 0, 0);
        sacc[g][sub] = z;
      }
    }
    __builtin_amdgcn_s_setprio(0);

    // exp + truncate to bf16, packed straight into PV A-frags (no LDS).
    // pf[g][c] slot j: j<4 -> key 32c+quad*4+j ; j>=4 -> key 32c+16+quad*4+j-4.
    short8 pf[2][2];
#pragma unroll
    for (int g = 0; g < 2; ++g)
#pragma unroll
      for (int c = 0; c < 2; ++c) {
        unsigned int w[4];
#pragma unroll
        for (int hs = 0; hs < 2; ++hs) {
          const floatx4 z = sacc[g][2 * c + hs];
          unsigned int u0 = __float_as_uint(__expf(z[0]));
          unsigned int u1 = __float_as_uint(__expf(z[1]));
          unsigned int u2 = __float_as_uint(__expf(z[2]));
          unsigned int u3 = __float_as_uint(__expf(z[3]));
          lsum[g] += __uint_as_float(u0 & 0xffff0000u);
          lsum[g] += __uint_as_float(u1 & 0xffff0000u);
          lsum[g] += __uint_as_float(u2 & 0xffff0000u);
          lsum[g] += __uint_as_float(u3 & 0xffff0000u);
          w[hs * 2 + 0] = (u0 >> 16) | (u1 & 0xffff0000u);
          w[hs * 2 + 1] = (u2 >> 16) | (u3 & 0xffff0000u);
        }
        union { unsigned int u[4]; short8 s; } pk;
        pk.u[0] = w[0]; pk.u[1] = w[1]; pk.u[2] = w[2]; pk.u[3] = w[3];
        pf[g][c] = pk.s;
      }

    // O += P * V. B-frag matches the pack permutation: two b64 reads per (sub,c).
    __builtin_amdgcn_s_setprio(1);
#pragma unroll
    for (int sub = 0; sub < 4; ++sub) {
      const int n = sub * 16 + l15;
      const int nsw = n & 7;
      const int inner = (quad & 1) * 4;  // shorts
      short8 vb[2];
#pragma unroll
      for (int c = 0; c < 2; ++c) {
        const int c8a = (((c << 2) | (quad >> 1)) ^ nsw);
        const int c8b = (((c << 2) | 2 | (quad >> 1)) ^ nsw);
        uintx2 a = *(const uintx2*)(myV + n * 64 + c8a * 8 + inner);
        uintx2 d = *(const uintx2*)(myV + n * 64 + c8b * 8 + inner);
        union { unsigned int u[4]; short8 s; } vk;
        vk.u[0] = a[0]; vk.u[1] = a[1]; vk.u[2] = d[0]; vk.u[3] = d[1];
        vb[c] = vk.s;
      }
#pragma unroll
      for (int g = 0; g < 2; ++g) {
        oacc[g][sub] = __builtin_amdgcn_mfma_f32_16x16x32_bf16(pf[g][0], vb[0], oacc[g][sub], 0, 0, 0);
        oacc[g][sub] = __builtin_amdgcn_mfma_f32_16x16x32_bf16(pf[g][1], vb[1], oacc[g][sub], 0, 0, 0);
      }
    }
    __builtin_amdgcn_s_setprio(0);
    __syncthreads();  // all reads done; next iter restages
  }

  // lsum: reduce across quads -> full khalf row-sum, replicated.
  float lh[2];
#pragma unroll
  for (int g = 0; g < 2; ++g) {
    float s = lsum[g];
    s += __shfl_xor(s, 16);
    s += __shfl_xor(s, 32);
    lh[g] = s;
  }
  if (lane < 16) {
#pragma unroll
    for (int g = 0; g < 2; ++g) lsb[khalf][qhalf * 32 + g * 16 + l15] = lh[g];
  }

  // cross-khalf merge; sK (dead) reused as the f32 O-partial buffer.
  float* obuf = (float*)&sK[0][0];
  if (khalf == 1) {
    float* my = obuf + qhalf * 2048;
#pragma unroll
    for (int g = 0; g < 2; ++g)
#pragma unroll
      for (int sub = 0; sub < 4; ++sub)
#pragma unroll
        for (int rr = 0; rr < 4; ++rr)
          my[(g * 16 + quad * 4 + rr) * 64 + sub * 16 + l15] = oacc[g][sub][rr];
  }
  __syncthreads();
  if (khalf == 0) {
    float* my = obuf + qhalf * 2048;
#pragma unroll
    for (int g = 0; g < 2; ++g) {
      float inv[4];
#pragma unroll
      for (int rr = 0; rr < 4; ++rr) {
        int idx = qhalf * 32 + g * 16 + quad * 4 + rr;
        inv[rr] = 1.f / (lsb[0][idx] + lsb[1][idx]);
      }
#pragma unroll
      for (int sub = 0; sub < 4; ++sub)
#pragma unroll
        for (int rr = 0; rr < 4; ++rr) {
          float v = oacc[g][sub][rr] + my[(g * 16 + quad * 4 + rr) * 64 + sub * 16 + l15];
          int row = b * SS + q0 + g * 16 + quad * 4 + rr;
          O[(size_t)row * DD + h * HD + sub * 16 + l15] = f2bf(v * inv[rr]);
        }
    }
  }
}

// ---------------------------------------------------------------------------
// Memory plan (unchanged from R4).
// ---------------------------------------------------------------------------
extern "C" void kernel_launch(void* const* d_in, const int* in_sizes, int n_in,
                              void* d_out, int out_size, void* d_ws, size_t ws_size,
                              hipStream_t stream) {
  const float* x       = (const float*)d_in[0];
  const float* w_in_l  = (const float*)d_in[1];
  const float* b_in_l  = (const float*)d_in[2];
  const float* w_out_l = (const float*)d_in[3];
  const float* b_out_l = (const float*)d_in[4];
  const float* w_in_g  = (const float*)d_in[5];
  const float* b_in_g  = (const float*)d_in[6];
  const float* w_out_g = (const float*)d_in[7];
  const float* b_out_g = (const float*)d_in[8];

  unsigned short* wsA = (unsigned short*)d_ws;            // 12M shorts
  unsigned short* wsB = wsA + (size_t)MM * TD;            // 4M shorts
  unsigned short* dob = (unsigned short*)d_out;           // 8M shorts
  unsigned short* wbf_out_l = dob;                        // 1M sh
  unsigned short* wbf_in_g  = dob + (size_t)DD * DD;      // 3M sh
  unsigned short* wbf_in_l  = dob + 4 * (size_t)DD * DD;  // 3M sh
  unsigned short* o1        = dob + 4 * (size_t)DD * DD;  // 4M sh (after g1)
  unsigned short* vtbuf     = dob;                        // 4M sh (after g4)

  dim3 blk(256);
  // fused weight/x converts: 512 + 1536 + 1536 + 2048 = 5632 blocks
  cvt_all<<<dim3(5632), blk, 0, stream>>>(w_out_l, wbf_out_l, 512,
                                          w_in_g, wbf_in_g, 1536,
                                          w_in_l, wbf_in_l, 1536,
                                          x, wsB, 2048);

  // 1) QKV1 = x @ w_in_l^T + b_in_l  (768 blocks, XCD-swizzled)
  gemm_bt_bias<128, 0><<<dim3(TD / 128, MM / 128), blk, 0, stream>>>(wsB, wbf_in_l, b_in_l, wsA, MM, TD, DD);
  // 2) local attention (rows pre-permuted for the reshape trick)
  attn_local<<<dim3(BB * CS * HH / 4), blk, 0, stream>>>(wsA, o1);
  // 3) loc2 = O1 @ w_out_l^T + b_out_l  (MT=64, 512 blocks, XCD-swizzled)
  gemm_bt_bias<64, 0><<<dim3(DD / 128, MM / 64), blk, 0, stream>>>(o1, wbf_out_l, b_out_l, wsB, MM, DD, DD);
  // 4) QKV2 = loc2 @ w_in_g^T + b_in_g  (768 blocks, XCD-swizzled)
  gemm_bt_bias<128, 0><<<dim3(TD / 128, MM / 128), blk, 0, stream>>>(wsB, wbf_in_g, b_in_g, wsA, MM, TD, DD);
  // 5a) V pre-transpose
  transpose_v<<<dim3(BB * HH, SS / 64), blk, 0, stream>>>(wsA, vtbuf);
  // 5b) global attention (final: reg-P, DMA staging, 4 blocks/CU, setprio)
  attn_global<<<dim3(BB * HH, SS / 64), blk, 0, stream>>>(wsA, wsA + DD, vtbuf, wsB);
  // 5c) convert w_out_g into dead QKV2 space
  cvt_bf16<<<dim3(DD * DD / 2048), blk, 0, stream>>>(w_out_g, wsA, DD * DD);
  // 6) out = O2 @ w_out_g^T + b_out_g  (f32 out, MT=64, XCD-swizzled)
  gemm_bt_bias<64, 1><<<dim3(DD / 128, MM / 64), blk, 0, stream>>>(wsB, wsA, b_out_g, d_out, MM, DD, DD);
}